// Round 1
// baseline (1889.136 us; speedup 1.0000x reference)
//
#include <hip/hip_runtime.h>

#define DM 1024
#define NH 16
#define DK 64
#define BB 4
#define TS 2048
#define MR (BB*TS)   // 8192 rows

typedef __attribute__((ext_vector_type(8))) short bf16x8;
typedef __attribute__((ext_vector_type(4))) float f32x4;
using u16 = unsigned short;

static __device__ __forceinline__ u16 f2bf(float f) {
  union { float fv; unsigned uv; } c; c.fv = f;
  unsigned u = c.uv;
  unsigned r = 0x7FFFu + ((u >> 16) & 1u);
  return (u16)((u + r) >> 16);
}

// ---------------- f32 -> bf16 conversion (vectorized) ----------------
__global__ __launch_bounds__(256) void cvt_bf16(const float* __restrict__ in,
                                                u16* __restrict__ out, int n4) {
  int i = blockIdx.x * 256 + threadIdx.x;
  if (i >= n4) return;
  const float4 v = reinterpret_cast<const float4*>(in)[i];
  union { u16 s[4]; unsigned long long ll; } o;
  o.s[0] = f2bf(v.x); o.s[1] = f2bf(v.y); o.s[2] = f2bf(v.z); o.s[3] = f2bf(v.w);
  reinterpret_cast<unsigned long long*>(out)[i] = o.ll;
}

// ---------------- bf16 NT GEMM: C[m][n] = sum_k A[m][k]*Bw[n][k] + bias[n] ---
// 128x128 tile, BK=32, 4 waves (2x2), wave tile 64x64 = 4x4 frags of 16x16.
// outb != null : write bf16 head-split [b,h,t,d], value*(scale) (QKV path)
// outb == null : write f32 (acc + bias + resid) row-major (out-proj path)
__global__ __launch_bounds__(256) void gemm_bt(
    const u16* __restrict__ A, const u16* __restrict__ Bw,
    const float* __restrict__ bias,
    u16* __restrict__ outb, float* __restrict__ outf,
    const float* __restrict__ resid, float scale)
{
  __shared__ u16 As[128 * 32];
  __shared__ u16 Bs[128 * 32];
  const int tid = threadIdx.x;
  const int tile_n = blockIdx.x * 128;
  const int tile_m = blockIdx.y * 128;
  const int wid = tid >> 6, lane = tid & 63;
  const int wr = wid >> 1, wc = wid & 1;
  const int g = lane >> 4, lr = lane & 15;

  // staging assignment: chunk c covers elements [c*8, c*8+8) of the 128x32 tile
  const int c0 = tid * 2, c1 = c0 + 1;
  const int r0 = c0 >> 2, k0 = (c0 & 3) * 8;
  const int r1 = c1 >> 2, k1 = (c1 & 3) * 8;

  const f32x4 fzero = {0.f, 0.f, 0.f, 0.f};
  f32x4 acc[4][4];
#pragma unroll
  for (int i = 0; i < 4; ++i)
#pragma unroll
    for (int j = 0; j < 4; ++j) acc[i][j] = fzero;

  uint4 va0 = *reinterpret_cast<const uint4*>(A + (size_t)(tile_m + r0) * DM + k0);
  uint4 va1 = *reinterpret_cast<const uint4*>(A + (size_t)(tile_m + r1) * DM + k1);
  uint4 vb0 = *reinterpret_cast<const uint4*>(Bw + (size_t)(tile_n + r0) * DM + k0);
  uint4 vb1 = *reinterpret_cast<const uint4*>(Bw + (size_t)(tile_n + r1) * DM + k1);

  for (int kt = 0; kt < DM; kt += 32) {
    __syncthreads();
    reinterpret_cast<uint4*>(As)[c0] = va0;
    reinterpret_cast<uint4*>(As)[c1] = va1;
    reinterpret_cast<uint4*>(Bs)[c0] = vb0;
    reinterpret_cast<uint4*>(Bs)[c1] = vb1;
    __syncthreads();
    if (kt + 32 < DM) {  // prefetch next K-tile while computing this one
      va0 = *reinterpret_cast<const uint4*>(A + (size_t)(tile_m + r0) * DM + kt + 32 + k0);
      va1 = *reinterpret_cast<const uint4*>(A + (size_t)(tile_m + r1) * DM + kt + 32 + k1);
      vb0 = *reinterpret_cast<const uint4*>(Bw + (size_t)(tile_n + r0) * DM + kt + 32 + k0);
      vb1 = *reinterpret_cast<const uint4*>(Bw + (size_t)(tile_n + r1) * DM + kt + 32 + k1);
    }
    bf16x8 af[4], bfr[4];
#pragma unroll
    for (int i = 0; i < 4; ++i)
      af[i] = *reinterpret_cast<const bf16x8*>(As + (wr * 64 + i * 16 + lr) * 32 + g * 8);
#pragma unroll
    for (int j = 0; j < 4; ++j)
      bfr[j] = *reinterpret_cast<const bf16x8*>(Bs + (wc * 64 + j * 16 + lr) * 32 + g * 8);
#pragma unroll
    for (int i = 0; i < 4; ++i)
#pragma unroll
      for (int j = 0; j < 4; ++j)
        acc[i][j] = __builtin_amdgcn_mfma_f32_16x16x32_bf16(af[i], bfr[j], acc[i][j], 0, 0, 0);
  }

#pragma unroll
  for (int j = 0; j < 4; ++j) {
    const int n = tile_n + wc * 64 + j * 16 + lr;
    const float bv = bias[n];
#pragma unroll
    for (int i = 0; i < 4; ++i) {
#pragma unroll
      for (int r = 0; r < 4; ++r) {
        const int m = tile_m + wr * 64 + i * 16 + g * 4 + r;
        float v = acc[i][j][r] + bv;
        if (outb) {
          const int b = m >> 11, t = m & 2047;
          const int h = n >> 6, d = n & 63;
          outb[((size_t)((b * NH + h) * TS + t)) * DK + d] = f2bf(v * scale);
        } else {
          const size_t idx = (size_t)m * DM + n;
          outf[idx] = v + resid[idx];
        }
      }
    }
  }
}

// ---------------- V [bh][t][d] -> Vt [bh][d][t] ----------------
__global__ __launch_bounds__(256) void transpose_v(const u16* __restrict__ V,
                                                   u16* __restrict__ Vt) {
  __shared__ u16 tile[64][65];
  const int bh = blockIdx.y;
  const int tt = blockIdx.x;
  const u16* src = V + ((size_t)bh * TS + tt * 64) * DK;
#pragma unroll
  for (int i = 0; i < 16; ++i) {
    int e = i * 256 + threadIdx.x;
    tile[e >> 6][e & 63] = src[e];
  }
  __syncthreads();
  u16* dst = Vt + (size_t)bh * DK * TS + tt * 64;
#pragma unroll
  for (int i = 0; i < 16; ++i) {
    int e = i * 256 + threadIdx.x;
    dst[(e >> 6) * TS + (e & 63)] = tile[e & 63][e >> 6];
  }
}

// ---------------- fused attention ----------------
// Q pre-scaled by log2(e)/8 so softmax uses exp2 with no max-tracking
// (softmax is shift/base invariant; |scores|<~3 so no overflow risk).
// Block = 4 waves; wave w owns q-rows [q0, q0+16). Two passes over K-tiles:
// pass1 accumulates denominator; pass2 recomputes S, writes weights (f32, the
// 1.07 GB output), and accumulates ctx = P·V via LDS round-trip for P frags.
__global__ __launch_bounds__(256) void attn_fused(
    const u16* __restrict__ Q, const u16* __restrict__ K, const u16* __restrict__ Vt,
    float* __restrict__ attn_out, u16* __restrict__ ctxb)
{
  __shared__ u16 Wl[4][16][64];  // per-wave P strip (bf16)
  const int tid = threadIdx.x;
  const int wid = tid >> 6, lane = tid & 63;
  const int g = lane >> 4, lr = lane & 15;
  const int bh = blockIdx.z * NH + blockIdx.y;
  const int q0 = blockIdx.x * 64 + wid * 16;
  const u16* Qh = Q + (size_t)bh * TS * DK;
  const u16* Kh = K + (size_t)bh * TS * DK;
  const u16* Vh = Vt + (size_t)bh * DK * TS;

  bf16x8 qf[2];
#pragma unroll
  for (int ks = 0; ks < 2; ++ks)
    qf[ks] = *reinterpret_cast<const bf16x8*>(Qh + (size_t)(q0 + lr) * DK + ks * 32 + g * 8);

  const f32x4 fzero = {0.f, 0.f, 0.f, 0.f};
  float lsum[4] = {0.f, 0.f, 0.f, 0.f};

  // pass 1: denominator only
  for (int kt = 0; kt < 32; ++kt) {
    const int s0 = kt * 64;
#pragma unroll
    for (int sf = 0; sf < 4; ++sf) {
      const u16* krow = Kh + (size_t)(s0 + sf * 16 + lr) * DK + g * 8;
      bf16x8 kf0 = *reinterpret_cast<const bf16x8*>(krow);
      bf16x8 kf1 = *reinterpret_cast<const bf16x8*>(krow + 32);
      f32x4 c = fzero;
      c = __builtin_amdgcn_mfma_f32_16x16x32_bf16(qf[0], kf0, c, 0, 0, 0);
      c = __builtin_amdgcn_mfma_f32_16x16x32_bf16(qf[1], kf1, c, 0, 0, 0);
#pragma unroll
      for (int r = 0; r < 4; ++r) lsum[r] += exp2f(c[r]);
    }
  }
#pragma unroll
  for (int r = 0; r < 4; ++r) {
    float s = lsum[r];
#pragma unroll
    for (int off = 1; off < 16; off <<= 1) s += __shfl_xor(s, off, 64);
    lsum[r] = 1.0f / s;   // reciprocal denominator, broadcast across 16-lane group
  }

  // pass 2: weights out + PV accumulate
  f32x4 ctx[4];
#pragma unroll
  for (int ni = 0; ni < 4; ++ni) ctx[ni] = fzero;

  for (int kt = 0; kt < 32; ++kt) {
    const int s0 = kt * 64;
    f32x4 sa[4];
#pragma unroll
    for (int sf = 0; sf < 4; ++sf) {
      const u16* krow = Kh + (size_t)(s0 + sf * 16 + lr) * DK + g * 8;
      bf16x8 kf0 = *reinterpret_cast<const bf16x8*>(krow);
      bf16x8 kf1 = *reinterpret_cast<const bf16x8*>(krow + 32);
      f32x4 c = fzero;
      c = __builtin_amdgcn_mfma_f32_16x16x32_bf16(qf[0], kf0, c, 0, 0, 0);
      c = __builtin_amdgcn_mfma_f32_16x16x32_bf16(qf[1], kf1, c, 0, 0, 0);
      sa[sf] = c;
    }
#pragma unroll
    for (int sf = 0; sf < 4; ++sf)
#pragma unroll
      for (int r = 0; r < 4; ++r) {
        const float w = exp2f(sa[sf][r]) * lsum[r];
        const int q = q0 + g * 4 + r;
        attn_out[((size_t)bh * TS + q) * TS + s0 + sf * 16 + lr] = w;
        Wl[wid][g * 4 + r][sf * 16 + lr] = f2bf(w);
      }
    __syncthreads();   // uniform across block; orders cross-lane LDS write->read
#pragma unroll
    for (int ks = 0; ks < 2; ++ks) {
      bf16x8 af = *reinterpret_cast<const bf16x8*>(&Wl[wid][lr][ks * 32 + g * 8]);
#pragma unroll
      for (int ni = 0; ni < 4; ++ni) {
        bf16x8 vf = *reinterpret_cast<const bf16x8*>(
            Vh + (size_t)(ni * 16 + lr) * TS + s0 + ks * 32 + g * 8);
        ctx[ni] = __builtin_amdgcn_mfma_f32_16x16x32_bf16(af, vf, ctx[ni], 0, 0, 0);
      }
    }
    __syncthreads();   // protect Wl from next iteration's writes
  }

  const int b = bh >> 4, h = bh & 15;
#pragma unroll
  for (int ni = 0; ni < 4; ++ni)
#pragma unroll
    for (int r = 0; r < 4; ++r) {
      const int q = q0 + g * 4 + r;
      ctxb[((size_t)(b * TS + q)) * DM + h * 64 + ni * 16 + lr] = f2bf(ctx[ni][r]);
    }
}

// ---------------- LayerNorm over rows of y_pre ----------------
__global__ __launch_bounds__(256) void ln_fused(const float* __restrict__ yp,
    const float* __restrict__ gw, const float* __restrict__ bw,
    float* __restrict__ out)
{
  const int row = blockIdx.x;
  const int tid = threadIdx.x;
  const float4 v = *reinterpret_cast<const float4*>(yp + (size_t)row * DM + tid * 4);
  float s = v.x + v.y + v.z + v.w;
  float sq = v.x * v.x + v.y * v.y + v.z * v.z + v.w * v.w;
#pragma unroll
  for (int off = 1; off < 64; off <<= 1) {
    s  += __shfl_xor(s, off, 64);
    sq += __shfl_xor(sq, off, 64);
  }
  __shared__ float ss[4], sq4[4];
  const int wid = tid >> 6;
  if ((tid & 63) == 0) { ss[wid] = s; sq4[wid] = sq; }
  __syncthreads();
  s = ss[0] + ss[1] + ss[2] + ss[3];
  sq = sq4[0] + sq4[1] + sq4[2] + sq4[3];
  const float mu = s * (1.0f / DM);
  const float var = sq * (1.0f / DM) - mu * mu;
  const float rs = rsqrtf(var + 1e-5f);
  const float4 gv = *reinterpret_cast<const float4*>(gw + tid * 4);
  const float4 bv = *reinterpret_cast<const float4*>(bw + tid * 4);
  float4 o;
  o.x = (v.x - mu) * rs * gv.x + bv.x;
  o.y = (v.y - mu) * rs * gv.y + bv.y;
  o.z = (v.z - mu) * rs * gv.z + bv.z;
  o.w = (v.w - mu) * rs * gv.w + bv.w;
  *reinterpret_cast<float4*>(out + (size_t)row * DM + tid * 4) = o;
}

extern "C" void kernel_launch(void* const* d_in, const int* in_sizes, int n_in,
                              void* d_out, int out_size, void* d_ws, size_t ws_size,
                              hipStream_t stream)
{
  const float* x   = (const float*)d_in[0];
  const float* Wq  = (const float*)d_in[1];
  const float* bq  = (const float*)d_in[2];
  const float* Wk  = (const float*)d_in[3];
  const float* bk  = (const float*)d_in[4];
  const float* Wv  = (const float*)d_in[5];
  const float* bv  = (const float*)d_in[6];
  const float* Wo  = (const float*)d_in[7];
  const float* bo  = (const float*)d_in[8];
  const float* lng = (const float*)d_in[9];
  const float* lnb = (const float*)d_in[10];

  float* y_out    = (float*)d_out;
  float* attn_out = (float*)d_out + (size_t)MR * DM;

  // workspace layout (byte offsets), total 136 MiB
  char* ws = (char*)d_ws;
  u16*  xb   = (u16*)(ws);                       // 16 MiB
  u16*  Wqb  = (u16*)(ws + (16u  << 20));        // 2 MiB each
  u16*  Wkb  = (u16*)(ws + (18u  << 20));
  u16*  Wvb  = (u16*)(ws + (20u  << 20));
  u16*  Wob  = (u16*)(ws + (22u  << 20));
  u16*  Qb   = (u16*)(ws + (24u  << 20));        // 16 MiB each
  u16*  Kb   = (u16*)(ws + (40u  << 20));
  u16*  Vb   = (u16*)(ws + (56u  << 20));
  u16*  Vtb  = (u16*)(ws + (72u  << 20));
  u16*  ctxb = (u16*)(ws + (88u  << 20));
  float* ypre = (float*)(ws + (104u << 20));     // 32 MiB

  cvt_bf16<<<MR * DM / 4 / 256, 256, 0, stream>>>(x,  xb,  MR * DM / 4);
  cvt_bf16<<<DM * DM / 4 / 256, 256, 0, stream>>>(Wq, Wqb, DM * DM / 4);
  cvt_bf16<<<DM * DM / 4 / 256, 256, 0, stream>>>(Wk, Wkb, DM * DM / 4);
  cvt_bf16<<<DM * DM / 4 / 256, 256, 0, stream>>>(Wv, Wvb, DM * DM / 4);
  cvt_bf16<<<DM * DM / 4 / 256, 256, 0, stream>>>(Wo, Wob, DM * DM / 4);

  // fold 1/sqrt(dk) and log2(e) into Q so attention uses exp2 directly
  const float qscale = 0.125f * 1.4426950408889634f;
  gemm_bt<<<dim3(8, 64), 256, 0, stream>>>(xb, Wqb, bq, Qb, nullptr, nullptr, qscale);
  gemm_bt<<<dim3(8, 64), 256, 0, stream>>>(xb, Wkb, bk, Kb, nullptr, nullptr, 1.0f);
  gemm_bt<<<dim3(8, 64), 256, 0, stream>>>(xb, Wvb, bv, Vb, nullptr, nullptr, 1.0f);

  transpose_v<<<dim3(32, 64), 256, 0, stream>>>(Vb, Vtb);

  attn_fused<<<dim3(32, NH, BB), 256, 0, stream>>>(Qb, Kb, Vtb, attn_out, ctxb);

  gemm_bt<<<dim3(8, 64), 256, 0, stream>>>(ctxb, Wob, bo, nullptr, ypre, x, 1.0f);

  ln_fused<<<MR, 256, 0, stream>>>(ypre, lng, lnb, y_out);
}